// Round 11
// baseline (302.366 us; speedup 1.0000x reference)
//
#include <hip/hip_runtime.h>
#include <hip/hip_bf16.h>
#include <stdint.h>
#include <type_traits>

#define DEVINL __device__ __forceinline__

typedef unsigned short u16;
typedef unsigned int   u32;
typedef short bf16x8 __attribute__((ext_vector_type(8)));
typedef float f32x4  __attribute__((ext_vector_type(4)));

// ---- problem constants ----
constexpr int BB   = 2,  SS  = 2048, HID = 2048, NH = 16;
constexpr int NOPE = 128, VD = 128, QHD = 192;
constexpr int QL   = 1536, KVL = 512;
constexpr int TOK  = BB * SS;            // 4096 tokens
constexpr int NCOMB = 2176;              // ac row stride
constexpr int NREAL = 2112;              // real combined output cols (1536+512+64)
constexpr float SCALE2    = 0.10412907368573824f;   // 192^-0.5 * log2(e)
constexpr float THR_RAW   = 105.0f;                 // ~11 / SCALE2 (defer-max, raw units)
constexpr float LN1E4_32  = 0.28782313662425575f;   // ln(10000)/32

DEVINL float bf2f(u16 u) { union { u32 u; float f; } v; v.u = (u32)u << 16; return v.f; }
DEVINL u16 f2bf(float f) {
  union { float f; u32 u; } v; v.f = f;
  u32 r = v.u + 0x7fffu + ((v.u >> 16) & 1u);
  return (u16)(r >> 16);
}
DEVINL u32 pack2(float a, float b) { return (u32)f2bf(a) | ((u32)f2bf(b) << 16); }
DEVINL u32 cvtpk(float lo, float hi) {
  u32 r;
  asm("v_cvt_pk_bf16_f32 %0, %1, %2" : "=v"(r) : "v"(lo), "v"(hi));
  return r;
}

DEVINL float fexp2(float x) {
#if __has_builtin(__builtin_amdgcn_exp2f)
  return __builtin_amdgcn_exp2f(x);
#else
  return __expf(x * 0.6931471805599453f);
#endif
}

DEVINL void gload_lds16(const u16* g, u16* l) {
  __builtin_amdgcn_global_load_lds(
      (const __attribute__((address_space(1))) void*)g,
      (__attribute__((address_space(3))) void*)l, 16, 0, 0);
}

// ---------------- merged fp32 -> bf16 conversion (6 segments, one launch) ----------------
__global__ __launch_bounds__(256)
void k_f2bf_all(const float* __restrict__ s0, const float* __restrict__ s1,
                const float* __restrict__ s2, const float* __restrict__ s3,
                const float* __restrict__ s4, const float* __restrict__ s5,
                u16* __restrict__ d0, u16* __restrict__ d1, u16* __restrict__ d2,
                u16* __restrict__ d3, u16* __restrict__ d4, u16* __restrict__ d5) {
  long g = ((long)blockIdx.x * 256 + threadIdx.x) * 4;
  const float* s; u16* d; long off;
  if (g < 8388608L)       { s = s0; d = d0; off = g; }
  else if (g < 11534336L) { s = s1; d = d1; off = g - 8388608L; }
  else if (g < 12713984L) { s = s2; d = d2; off = g - 11534336L; }
  else if (g < 17432576L) { s = s3; d = d3; off = g - 12713984L; }
  else if (g < 19529728L) { s = s4; d = d4; off = g - 17432576L; }
  else                    { s = s5; d = d5; off = g - 19529728L; }
  float4 v = *(const float4*)(s + off);
  uint2 o; o.x = pack2(v.x, v.y); o.y = pack2(v.z, v.w);
  *(uint2*)(d + off) = o;
}

// ---------------- 128x128 2-phase counted-vmcnt NT GEMM body ----------------
template <class EPI>
DEVINL void gemm128_body(const u16* __restrict__ A, const u16* __restrict__ Bw,
                         int K, int m0, int n0, u16* SA, u16* SB, EPI epi) {
  const int t = threadIdx.x;           // 256 threads
  const int lane = t & 63, wave = t >> 6;
  const int wr = wave >> 1, wc = wave & 1;
  const int lq = lane & 15, lg = lane >> 4;
  const int NT = K >> 6;

  auto stage = [&](const u16* g, u16* l) {
#pragma unroll
    for (int i = 0; i < 4; ++i) {      // 1024 16B chunks, 4/thread
      int c = i * 256 + t, row = c >> 3;
      gload_lds16(g + (size_t)row * K + ((c & 7) ^ (row & 7)) * 8, l + c * 8);
    }
  };
  auto stageA = [&](int d, int kt) { stage(A + (size_t)m0 * K + kt * 64, SA + d * 8192); };
  auto stageB = [&](int d, int kt) { stage(Bw + (size_t)n0 * K + kt * 64, SB + d * 8192); };
  auto rdA = [&](int d, int m, int k) -> bf16x8 {
    int row = wr * 64 + m * 16 + lq;
    return *(const bf16x8*)(SA + d * 8192 + row * 64 + (((k * 4 + lg) ^ (row & 7)) * 8));
  };
  auto rdB = [&](int d, int n, int k) -> bf16x8 {
    int row = wc * 64 + n * 16 + lq;
    return *(const bf16x8*)(SB + d * 8192 + row * 64 + (((k * 4 + lg) ^ (row & 7)) * 8));
  };

  f32x4 acc[4][4] = {};
  bf16x8 a[4][2], b[4][2];

  stageA(0, 0); stageB(0, 0);
  if (NT > 1) stageA(1, 1);
  asm volatile("s_waitcnt vmcnt(4)" ::: "memory");
  __builtin_amdgcn_s_barrier();

  for (int T = 0; T < NT; ++T) {
    const int d = T & 1;
#pragma unroll
    for (int m = 0; m < 4; ++m) { a[m][0] = rdA(d, m, 0); a[m][1] = rdA(d, m, 1); }
#pragma unroll
    for (int n = 0; n < 2; ++n) { b[n][0] = rdB(d, n, 0); b[n][1] = rdB(d, n, 1); }
    if (T + 1 < NT) stageB(d ^ 1, T + 1);
    asm volatile("s_waitcnt lgkmcnt(0)" ::: "memory");
#pragma unroll
    for (int m = 0; m < 4; ++m)
#pragma unroll
      for (int n = 0; n < 2; ++n) {
        acc[m][n] = __builtin_amdgcn_mfma_f32_16x16x32_bf16(a[m][0], b[n][0], acc[m][n], 0, 0, 0);
        acc[m][n] = __builtin_amdgcn_mfma_f32_16x16x32_bf16(a[m][1], b[n][1], acc[m][n], 0, 0, 0);
      }
    __builtin_amdgcn_s_barrier();      // B1
#pragma unroll
    for (int n = 2; n < 4; ++n) { b[n][0] = rdB(d, n, 0); b[n][1] = rdB(d, n, 1); }
    if (T + 2 < NT) stageA(d, T + 2);
    asm volatile("s_waitcnt lgkmcnt(0)" ::: "memory");
#pragma unroll
    for (int m = 0; m < 4; ++m)
#pragma unroll
      for (int n = 2; n < 4; ++n) {
        acc[m][n] = __builtin_amdgcn_mfma_f32_16x16x32_bf16(a[m][0], b[n][0], acc[m][n], 0, 0, 0);
        acc[m][n] = __builtin_amdgcn_mfma_f32_16x16x32_bf16(a[m][1], b[n][1], acc[m][n], 0, 0, 0);
      }
    if (T + 2 < NT)      asm volatile("s_waitcnt vmcnt(4)" ::: "memory");
    else if (T + 1 < NT) asm volatile("s_waitcnt vmcnt(0)" ::: "memory");
    __builtin_amdgcn_s_barrier();      // B2
  }

#pragma unroll
  for (int m = 0; m < 4; ++m)
#pragma unroll
    for (int n = 0; n < 4; ++n)
      epi(m0 + wr * 64 + m * 16 + lg * 4, n0 + wc * 64 + n * 16 + lq, acc[m][n]);
}

// GEMM1: hidden @ w_comb^T -> ac. 544 blocks; XCD-chunked decode (m-fastest).
__global__ __launch_bounds__(256, 2)
void k_gemm1(const u16* __restrict__ A, const u16* __restrict__ Bw, u16* __restrict__ C) {
  __shared__ u16 SA[2 * 8192];
  __shared__ u16 SB[2 * 8192];
  const int L = (blockIdx.x & 7) * 68 + (blockIdx.x >> 3);
  const int n0 = (L >> 5) * 128, m0 = (L & 31) * 128;
  auto epi = [&](int row, int col, const f32x4& v) {
    if (col < NREAL) {
#pragma unroll
      for (int r = 0; r < 4; ++r) C[(size_t)(row + r) * NCOMB + col] = f2bf(v[r]);
    }
  };
  gemm128_body(A, Bw, HID, m0, n0, SA, SB, epi);
}

// grouped qb (768 blocks) + kvb (1024 blocks, epilogue splits KN / VT-transposed)
__global__ __launch_bounds__(256, 2)
void k_gemm_qbkvb(const u16* __restrict__ qa_n, const u16* __restrict__ w_qb,
                  u16* __restrict__ qfull, const u16* __restrict__ kv_n,
                  const u16* __restrict__ w_kvb, u16* __restrict__ KN,
                  u16* __restrict__ VT) {
  __shared__ u16 SA[2 * 8192];
  __shared__ u16 SB[2 * 8192];
  const int bx = blockIdx.x;
  if (bx < 768) {
    const int L = (bx & 7) * 96 + (bx >> 3);
    const int n0 = (L >> 5) * 128, m0 = (L & 31) * 128;
    auto epi = [&](int row, int col, const f32x4& v) {
#pragma unroll
      for (int r = 0; r < 4; ++r) qfull[(size_t)(row + r) * 3072 + col] = f2bf(v[r]);
    };
    gemm128_body(qa_n, w_qb, QL, m0, n0, SA, SB, epi);
  } else {
    const int i = bx - 768;
    const int L = (i & 7) * 128 + (i >> 3);
    const int n0 = (L >> 5) * 128, m0 = (L & 31) * 128;
    auto epi = [&](int row, int col, const f32x4& v) {
      const int h = col >> 8, d = col & 255;
      if (d < 128) {
#pragma unroll
        for (int r = 0; r < 4; ++r) KN[(size_t)(row + r) * 2048 + h * 128 + d] = f2bf(v[r]);
      } else {
        uint2 o; o.x = pack2(v[0], v[1]); o.y = pack2(v[2], v[3]);
        *(uint2*)(VT + ((size_t)((row >> 11) * 16 + h) * 128 + (d - 128)) * SS + (row & (SS - 1))) = o;
      }
    };
    gemm128_body(kv_n, w_kvb, KVL, m0, n0, SA, SB, epi);
  }
}

// o_proj -> fp32 d_out. 512 blocks = exactly 2/CU.
__global__ __launch_bounds__(256, 2)
void k_oproj(const u16* __restrict__ A, const u16* __restrict__ Bw, float* __restrict__ C) {
  __shared__ u16 SA[2 * 8192];
  __shared__ u16 SB[2 * 8192];
  const int L = (blockIdx.x & 7) * 64 + (blockIdx.x >> 3);
  const int n0 = (L >> 5) * 128, m0 = (L & 31) * 128;
  auto epi = [&](int row, int col, const f32x4& v) {
#pragma unroll
    for (int r = 0; r < 4; ++r) C[(size_t)(row + r) * HID + col] = v[r];
  };
  gemm128_body(A, Bw, NH * VD, m0, n0, SA, SB, epi);
}

// ---------------- fused per-token: RMSNorm(q), RMSNorm(kv), rope(k_pe) ----------------
__global__ __launch_bounds__(256)
void k_token(const u16* __restrict__ ac, const float* __restrict__ qw,
             const float* __restrict__ kvw, const int* __restrict__ pos,
             u16* __restrict__ qa_n, u16* __restrict__ kv_n, u16* __restrict__ peR) {
  const int row = blockIdx.x, t = threadIdx.x;
  const u16* xr = ac + (size_t)row * NCOMB;
  float sq = 0.f, skv = 0.f;
  if (t < 192) {
    bf16x8 v = *(const bf16x8*)(xr + t * 8);
#pragma unroll
    for (int j = 0; j < 8; ++j) { float f = bf2f((u16)v[j]); sq += f * f; }
  }
  if (t < 64) {
    bf16x8 v = *(const bf16x8*)(xr + QL + t * 8);
#pragma unroll
    for (int j = 0; j < 8; ++j) { float f = bf2f((u16)v[j]); skv += f * f; }
  }
#pragma unroll
  for (int o = 1; o < 64; o <<= 1) { sq += __shfl_xor(sq, o); skv += __shfl_xor(skv, o); }
  __shared__ float red[4][2];
  if ((t & 63) == 0) { red[t >> 6][0] = sq; red[t >> 6][1] = skv; }
  __syncthreads();
  const float rsq  = rsqrtf((red[0][0] + red[1][0] + red[2][0] + red[3][0]) / (float)QL  + 1e-6f);
  const float rskv = rsqrtf((red[0][1] + red[1][1] + red[2][1] + red[3][1]) / (float)KVL + 1e-6f);
  if (t < 192) {
    bf16x8 v = *(const bf16x8*)(xr + t * 8);
    u32 o4[4];
#pragma unroll
    for (int j = 0; j < 4; ++j)
      o4[j] = pack2(bf2f((u16)v[2 * j]) * rsq * qw[t * 8 + 2 * j],
                    bf2f((u16)v[2 * j + 1]) * rsq * qw[t * 8 + 2 * j + 1]);
    *(uint4*)(qa_n + (size_t)row * QL + t * 8) = *(uint4*)o4;
  }
  if (t < 64) {
    bf16x8 v = *(const bf16x8*)(xr + QL + t * 8);
    u32 o4[4];
#pragma unroll
    for (int j = 0; j < 4; ++j)
      o4[j] = pack2(bf2f((u16)v[2 * j]) * rskv * kvw[t * 8 + 2 * j],
                    bf2f((u16)v[2 * j + 1]) * rskv * kvw[t * 8 + 2 * j + 1]);
    *(uint4*)(kv_n + (size_t)row * KVL + t * 8) = *(uint4*)o4;
  }
  if (t < 32) {
    const u16* src = xr + (QL + KVL) + 2 * t;
    float x0 = bf2f(src[0]), x1 = bf2f(src[1]);
    float ang = (float)pos[row] * __expf(-(float)t * LN1E4_32);
    float sn, cs; sincosf(ang, &sn, &cs);
    *(u32*)(peR + (size_t)row * 64 + 2 * t) = pack2(x0 * cs - x1 * sn, x1 * cs + x0 * sn);
  }
}

// ---------------- causal flash attention: single-buffered V -> 36KB LDS -> 4 blocks/CU ----------------
// 1024 blocks x 4 waves. V(tt) issued at tile start (before K(tt+1)); mid-tile
// vmcnt(3)+barrier retires exactly the 2 oldest (V) loads collectively; end-tile
// vmcnt(0)+barrier retires K(tt+1) and protects the Vs overwrite.
// id map: bh = (id&7)+8*((id>>3)&3) (bh const per CU; 4 c's per CU summing 62 ->
// uniform per-CU work under all-resident 4/CU occupancy; ids 0..255 heaviest).
__global__ __launch_bounds__(256)
void k_attn(const u16* __restrict__ Qf, const u16* __restrict__ KN,
            const u16* __restrict__ peR, const u16* __restrict__ VT,
            const int* __restrict__ pos, u16* __restrict__ Oa) {
  const int id = blockIdx.x;
  const int v5 = id >> 5;
  const int c = (v5 < 8) ? (31 - v5) : (v5 < 16) ? (v5 - 8) : (v5 < 24) ? (39 - v5) : (v5 - 16);
  const int bh = (id & 7) + 8 * ((id >> 3) & 3);
  const int b = bh >> 4, h = bh & 15;
  const int t = threadIdx.x, lane = t & 63, wave = t >> 6;
  const int lq = lane & 15, lg = lane >> 4;
  const int q0 = c * 64 + wave * 16;
  const size_t vb = (size_t)bh * VD * SS;

  __shared__ u16 Ks[2][32 * 192];     // 24 KB, double-buffered
  __shared__ u16 Vs[128 * 32];        //  8 KB, single-buffered
  __shared__ u16 Pl[4][512];          //  4 KB
  char* pl = (char*)&Pl[wave][0];
  const int swq = ((lq ^ (lq >> 2)) & 3) << 4;

  auto stageK = [&](int buf, int kb) {
#pragma unroll
    for (int i = 0; i < 3; ++i) {      // 768 16B chunks (nope from KN, pe from peR)
      int cc = t + 256 * i, row = cc / 24, sl = cc % 24;
      int sg = sl ^ (row & 7);
      const u16* src = (sg < 16)
          ? KN + (size_t)(b * SS + kb + row) * 2048 + h * 128 + sg * 8
          : peR + (size_t)(b * SS + kb + row) * 64 + (sg - 16) * 8;
      gload_lds16(src, &Ks[buf][0] + cc * 8);
    }
  };
  auto stageV = [&](int kb) {
#pragma unroll
    for (int i = 0; i < 2; ++i) {      // 512 16B chunks
      int cc = t + 256 * i, row = cc >> 2, sl = cc & 3;
      gload_lds16(VT + vb + (size_t)row * SS + kb + (sl ^ ((row >> 1) & 3)) * 8,
                  &Vs[0] + cc * 8);
    }
  };

  const int token = b * SS + q0 + lq;
  bf16x8 qf[6];
#pragma unroll
  for (int ch = 0; ch < 6; ++ch)
    qf[ch] = *(const bf16x8*)(Qf + (size_t)token * (NH * QHD) + h * QHD + ch * 32 + lg * 8);
  const float posv = (float)pos[token];
#pragma unroll
  for (int ch = 4; ch < 6; ++ch)
#pragma unroll
    for (int p = 0; p < 4; ++p) {
      const int jj = (ch - 4) * 16 + lg * 4 + p;
      const float ang = posv * __expf(-(float)jj * LN1E4_32);
      float sn, cs; sincosf(ang, &sn, &cs);
      const float x0 = bf2f((u16)qf[ch][2 * p]), x1 = bf2f((u16)qf[ch][2 * p + 1]);
      qf[ch][2 * p]     = (short)f2bf(x0 * cs - x1 * sn);
      qf[ch][2 * p + 1] = (short)f2bf(x1 * cs + x0 * sn);
    }

  float m = -1e30f, lsum = 0.f;     // m in RAW score units
  f32x4 o[8];
#pragma unroll
  for (int vc = 0; vc < 8; ++vc) o[vc] = (f32x4){0.f, 0.f, 0.f, 0.f};

  const int nt = 2 * (c + 1);

  stageK(0, 0);
  asm volatile("s_waitcnt vmcnt(0)" ::: "memory");
  __builtin_amdgcn_s_barrier();

  for (int tt = 0; tt < nt; ++tt) {
    const int cur = tt & 1;
    const int kb = tt * 32;
    const bool more = (tt + 1 < nt);
    stageV(kb);                           // issued FIRST (oldest in vmcnt FIFO)
    if (more) stageK(cur ^ 1, kb + 32);

    const bool comp = (kb < q0 + 16);
    float p0, p1, p2, p3, p4, p5, p6, p7;
    if (comp) {
      f32x4 slo = (f32x4){0.f, 0.f, 0.f, 0.f};
      f32x4 shi = (f32x4){0.f, 0.f, 0.f, 0.f};
      __builtin_amdgcn_s_setprio(1);
#pragma unroll
      for (int ch = 0; ch < 6; ++ch) {
        const int ps = (ch * 4 + lg) ^ (lq & 7);
        bf16x8 klo = *(const bf16x8*)(&Ks[cur][0] + (lq * 24 + ps) * 8);
        bf16x8 khi = *(const bf16x8*)(&Ks[cur][0] + ((16 + lq) * 24 + ps) * 8);
        slo = __builtin_amdgcn_mfma_f32_16x16x32_bf16(klo, qf[ch], slo, 0, 0, 0);
        shi = __builtin_amdgcn_mfma_f32_16x16x32_bf16(khi, qf[ch], shi, 0, 0, 0);
      }
      __builtin_amdgcn_s_setprio(0);

      float mx;
      if (kb + 32 <= q0) {
        mx = fmaxf(fmaxf(fmaxf(slo[0], slo[1]), fmaxf(slo[2], slo[3])),
                   fmaxf(fmaxf(shi[0], shi[1]), fmaxf(shi[2], shi[3])));
      } else {
        const int qrow = q0 + lq;
#pragma unroll
        for (int r = 0; r < 4; ++r) {
          int klo = kb + lg * 4 + r;
          slo[r] = (klo <= qrow)        ? slo[r] : -3e38f;
          shi[r] = ((klo + 16) <= qrow) ? shi[r] : -3e38f;
        }
        mx = fmaxf(fmaxf(fmaxf(slo[0], slo[1]), fmaxf(slo[2], slo[3])),
                   fmaxf(fmaxf(shi[0], shi[1]), fmaxf(shi[2], shi[3])));
      }
      mx = fmaxf(mx, __shfl_xor(mx, 16));
      mx = fmaxf(mx, __shfl_xor(mx, 32));
      if (!__all(mx - m <= THR_RAW)) {
        float mnew = fmaxf(m, mx);
        float fac = fexp2((m - mnew) * SCALE2);
        lsum *= fac;
#pragma unroll
        for (int vc = 0; vc < 8; ++vc) {
          o[vc][0] *= fac; o[vc][1] *= fac; o[vc][2] *= fac; o[vc][3] *= fac;
        }
        m = mnew;
      }
      const float ms = m * SCALE2;
      p0 = fexp2(fmaf(slo[0], SCALE2, -ms)); p1 = fexp2(fmaf(slo[1], SCALE2, -ms));
      p2 = fexp2(fmaf(slo[2], SCALE2, -ms)); p3 = fexp2(fmaf(slo[3], SCALE2, -ms));
      p4 = fexp2(fmaf(shi[0], SCALE2, -ms)); p5 = fexp2(fmaf(shi[1], SCALE2, -ms));
      p6 = fexp2(fmaf(shi[2], SCALE2, -ms)); p7 = fexp2(fmaf(shi[3], SCALE2, -ms));
      float ps2 = ((p0 + p1) + (p2 + p3)) + ((p4 + p5) + (p6 + p7));
      ps2 += __shfl_xor(ps2, 16);
      ps2 += __shfl_xor(ps2, 32);
      lsum += ps2;
    }

    // V(tt) collectively visible: retire the 2 oldest loads (V) in every thread.
    if (more) asm volatile("s_waitcnt vmcnt(3)" ::: "memory");
    else      asm volatile("s_waitcnt vmcnt(0)" ::: "memory");
    __builtin_amdgcn_s_barrier();

    if (comp) {
      *(u32*)(pl + lq * 64 + ((8 * lg)          ^ swq)) = cvtpk(p0, p1);
      *(u32*)(pl + lq * 64 + ((8 * lg + 4)      ^ swq)) = cvtpk(p2, p3);
      *(u32*)(pl + lq * 64 + ((32 + 8 * lg)     ^ swq)) = cvtpk(p4, p5);
      *(u32*)(pl + lq * 64 + ((32 + 8 * lg + 4) ^ swq)) = cvtpk(p6, p7);
      bf16x8 pf = *(const bf16x8*)(pl + lq * 64 + ((16 * lg) ^ swq));
      __builtin_amdgcn_s_setprio(1);
#pragma unroll
      for (int vc = 0; vc < 8; ++vc) {
        const int rv = vc * 16 + lq;
        const int psv = lg ^ ((rv >> 1) & 3);
        bf16x8 vf = *(const bf16x8*)(&Vs[0] + rv * 32 + psv * 8);
        o[vc] = __builtin_amdgcn_mfma_f32_16x16x32_bf16(vf, pf, o[vc], 0, 0, 0);
      }
      __builtin_amdgcn_s_setprio(0);
    }

    // K(tt+1) landed; all waves past PV reads of Vs -> next stageV may overwrite.
    if (more) asm volatile("s_waitcnt vmcnt(0)" ::: "memory");
    __builtin_amdgcn_s_barrier();
  }

  const float inv = 1.0f / lsum;
  u16* orow = Oa + (size_t)token * (NH * VD) + h * VD;
#pragma unroll
  for (int vc = 0; vc < 8; ++vc) {
    *(u32*)(orow + vc * 16 + lg * 4)     = cvtpk(o[vc][0] * inv, o[vc][1] * inv);
    *(u32*)(orow + vc * 16 + lg * 4 + 2) = cvtpk(o[vc][2] * inv, o[vc][3] * inv);
  }
}

// ---------------- host launch ----------------
extern "C" void kernel_launch(void* const* d_in, const int* in_sizes, int n_in,
                              void* d_out, int out_size, void* d_ws, size_t ws_size,
                              hipStream_t stream) {
  (void)in_sizes; (void)n_in; (void)out_size; (void)ws_size;
  const float* hidden  = (const float*)d_in[0];
  const int*   pos     = (const int*)d_in[2];
  const float* q_a_w   = (const float*)d_in[3];
  const float* q_a_ln  = (const float*)d_in[4];
  const float* q_b_w   = (const float*)d_in[5];
  const float* kv_a_w  = (const float*)d_in[6];
  const float* kv_a_ln = (const float*)d_in[7];
  const float* kv_b_w  = (const float*)d_in[8];
  const float* o_w     = (const float*)d_in[9];

  char* ws = (char*)d_ws;
  u16* hid_bf = (u16*)(ws + 0);          // dead after GEMM1; region reused as VT
  u16* VT     = (u16*)(ws + 0);
  u16* w_comb = (u16*)(ws + 16777216);
  u16* w_qb   = (u16*)(ws + 25690112);
  u16* w_kvb  = (u16*)(ws + 35127296);
  u16* w_o    = (u16*)(ws + 39321600);
  u16* ac     = (u16*)(ws + 47710208);   // dead after k_token; reused as attn_o
  u16* attn_o = (u16*)(ws + 47710208);
  u16* qa_n   = (u16*)(ws + 65536000);
  u16* kv_n   = (u16*)(ws + 78118912);
  u16* qfull  = (u16*)(ws + 82313216);
  u16* KN     = (u16*)(ws + 107479040);  // TOK x 2048 compact k_nope
  u16* peR    = (u16*)(ws + 141033472);  // TOK x 64 roped k_pe

  k_f2bf_all<<<23168, 256, 0, stream>>>(hidden, q_a_w, kv_a_w, q_b_w, kv_b_w, o_w,
                                        hid_bf, w_comb, w_comb + QL * HID, w_qb, w_kvb, w_o);
  k_gemm1<<<544, 256, 0, stream>>>(hid_bf, w_comb, ac);
  k_token<<<TOK, 256, 0, stream>>>(ac, q_a_ln, kv_a_ln, pos, qa_n, kv_n, peR);
  k_gemm_qbkvb<<<1792, 256, 0, stream>>>(qa_n, w_qb, qfull, kv_n, w_kvb, KN, VT);
  k_attn<<<1024, 256, 0, stream>>>(qfull, KN, peR, VT, pos, attn_o);
  k_oproj<<<512, 256, 0, stream>>>(attn_o, w_o, (float*)d_out);
}

// Round 12
// 297.370 us; speedup vs baseline: 1.0168x; 1.0168x over previous
//
#include <hip/hip_runtime.h>
#include <hip/hip_bf16.h>
#include <stdint.h>
#include <type_traits>

#define DEVINL __device__ __forceinline__

typedef unsigned short u16;
typedef unsigned int   u32;
typedef short bf16x8 __attribute__((ext_vector_type(8)));
typedef float f32x4  __attribute__((ext_vector_type(4)));

// ---- problem constants ----
constexpr int BB   = 2,  SS  = 2048, HID = 2048, NH = 16;
constexpr int NOPE = 128, VD = 128, QHD = 192;
constexpr int QL   = 1536, KVL = 512;
constexpr int TOK  = BB * SS;            // 4096 tokens
constexpr int NCOMB = 2176;              // ac row stride
constexpr int NREAL = 2112;              // real combined output cols (1536+512+64)
constexpr float SCALE2    = 0.10412907368573824f;   // 192^-0.5 * log2(e)
constexpr float THR_RAW   = 105.0f;                 // ~11 / SCALE2 (defer-max, raw units)
constexpr float LN1E4_32  = 0.28782313662425575f;   // ln(10000)/32

DEVINL float bf2f(u16 u) { union { u32 u; float f; } v; v.u = (u32)u << 16; return v.f; }
DEVINL u16 f2bf(float f) {
  union { float f; u32 u; } v; v.f = f;
  u32 r = v.u + 0x7fffu + ((v.u >> 16) & 1u);
  return (u16)(r >> 16);
}
DEVINL u32 pack2(float a, float b) { return (u32)f2bf(a) | ((u32)f2bf(b) << 16); }
DEVINL u32 cvtpk(float lo, float hi) {
  u32 r;
  asm("v_cvt_pk_bf16_f32 %0, %1, %2" : "=v"(r) : "v"(lo), "v"(hi));
  return r;
}

DEVINL float fexp2(float x) {
#if __has_builtin(__builtin_amdgcn_exp2f)
  return __builtin_amdgcn_exp2f(x);
#else
  return __expf(x * 0.6931471805599453f);
#endif
}

DEVINL void gload_lds16(const u16* g, u16* l) {
  __builtin_amdgcn_global_load_lds(
      (const __attribute__((address_space(1))) void*)g,
      (__attribute__((address_space(3))) void*)l, 16, 0, 0);
}

// ---------------- merged fp32 -> bf16 conversion (6 segments, one launch) ----------------
__global__ __launch_bounds__(256)
void k_f2bf_all(const float* __restrict__ s0, const float* __restrict__ s1,
                const float* __restrict__ s2, const float* __restrict__ s3,
                const float* __restrict__ s4, const float* __restrict__ s5,
                u16* __restrict__ d0, u16* __restrict__ d1, u16* __restrict__ d2,
                u16* __restrict__ d3, u16* __restrict__ d4, u16* __restrict__ d5) {
  long g = ((long)blockIdx.x * 256 + threadIdx.x) * 4;
  const float* s; u16* d; long off;
  if (g < 8388608L)       { s = s0; d = d0; off = g; }
  else if (g < 11534336L) { s = s1; d = d1; off = g - 8388608L; }
  else if (g < 12713984L) { s = s2; d = d2; off = g - 11534336L; }
  else if (g < 17432576L) { s = s3; d = d3; off = g - 12713984L; }
  else if (g < 19529728L) { s = s4; d = d4; off = g - 17432576L; }
  else                    { s = s5; d = d5; off = g - 19529728L; }
  float4 v = *(const float4*)(s + off);
  uint2 o; o.x = pack2(v.x, v.y); o.y = pack2(v.z, v.w);
  *(uint2*)(d + off) = o;
}

// ---------------- 128x128 2-phase counted-vmcnt NT GEMM body ----------------
template <class EPI>
DEVINL void gemm128_body(const u16* __restrict__ A, const u16* __restrict__ Bw,
                         int K, int m0, int n0, u16* SA, u16* SB, EPI epi) {
  const int t = threadIdx.x;           // 256 threads
  const int lane = t & 63, wave = t >> 6;
  const int wr = wave >> 1, wc = wave & 1;
  const int lq = lane & 15, lg = lane >> 4;
  const int NT = K >> 6;

  auto stage = [&](const u16* g, u16* l) {
#pragma unroll
    for (int i = 0; i < 4; ++i) {      // 1024 16B chunks, 4/thread
      int c = i * 256 + t, row = c >> 3;
      gload_lds16(g + (size_t)row * K + ((c & 7) ^ (row & 7)) * 8, l + c * 8);
    }
  };
  auto stageA = [&](int d, int kt) { stage(A + (size_t)m0 * K + kt * 64, SA + d * 8192); };
  auto stageB = [&](int d, int kt) { stage(Bw + (size_t)n0 * K + kt * 64, SB + d * 8192); };
  auto rdA = [&](int d, int m, int k) -> bf16x8 {
    int row = wr * 64 + m * 16 + lq;
    return *(const bf16x8*)(SA + d * 8192 + row * 64 + (((k * 4 + lg) ^ (row & 7)) * 8));
  };
  auto rdB = [&](int d, int n, int k) -> bf16x8 {
    int row = wc * 64 + n * 16 + lq;
    return *(const bf16x8*)(SB + d * 8192 + row * 64 + (((k * 4 + lg) ^ (row & 7)) * 8));
  };

  f32x4 acc[4][4] = {};
  bf16x8 a[4][2], b[4][2];

  stageA(0, 0); stageB(0, 0);
  if (NT > 1) stageA(1, 1);
  asm volatile("s_waitcnt vmcnt(4)" ::: "memory");
  __builtin_amdgcn_s_barrier();

  for (int T = 0; T < NT; ++T) {
    const int d = T & 1;
#pragma unroll
    for (int m = 0; m < 4; ++m) { a[m][0] = rdA(d, m, 0); a[m][1] = rdA(d, m, 1); }
#pragma unroll
    for (int n = 0; n < 2; ++n) { b[n][0] = rdB(d, n, 0); b[n][1] = rdB(d, n, 1); }
    if (T + 1 < NT) stageB(d ^ 1, T + 1);
    asm volatile("s_waitcnt lgkmcnt(0)" ::: "memory");
#pragma unroll
    for (int m = 0; m < 4; ++m)
#pragma unroll
      for (int n = 0; n < 2; ++n) {
        acc[m][n] = __builtin_amdgcn_mfma_f32_16x16x32_bf16(a[m][0], b[n][0], acc[m][n], 0, 0, 0);
        acc[m][n] = __builtin_amdgcn_mfma_f32_16x16x32_bf16(a[m][1], b[n][1], acc[m][n], 0, 0, 0);
      }
    __builtin_amdgcn_s_barrier();      // B1
#pragma unroll
    for (int n = 2; n < 4; ++n) { b[n][0] = rdB(d, n, 0); b[n][1] = rdB(d, n, 1); }
    if (T + 2 < NT) stageA(d, T + 2);
    asm volatile("s_waitcnt lgkmcnt(0)" ::: "memory");
#pragma unroll
    for (int m = 0; m < 4; ++m)
#pragma unroll
      for (int n = 2; n < 4; ++n) {
        acc[m][n] = __builtin_amdgcn_mfma_f32_16x16x32_bf16(a[m][0], b[n][0], acc[m][n], 0, 0, 0);
        acc[m][n] = __builtin_amdgcn_mfma_f32_16x16x32_bf16(a[m][1], b[n][1], acc[m][n], 0, 0, 0);
      }
    if (T + 2 < NT)      asm volatile("s_waitcnt vmcnt(4)" ::: "memory");
    else if (T + 1 < NT) asm volatile("s_waitcnt vmcnt(0)" ::: "memory");
    __builtin_amdgcn_s_barrier();      // B2
  }

#pragma unroll
  for (int m = 0; m < 4; ++m)
#pragma unroll
    for (int n = 0; n < 4; ++n)
      epi(m0 + wr * 64 + m * 16 + lg * 4, n0 + wc * 64 + n * 16 + lq, acc[m][n]);
}

// GEMM1: hidden @ w_comb^T -> ac. 544 blocks; XCD-chunked decode (m-fastest).
__global__ __launch_bounds__(256, 2)
void k_gemm1(const u16* __restrict__ A, const u16* __restrict__ Bw, u16* __restrict__ C) {
  __shared__ u16 SA[2 * 8192];
  __shared__ u16 SB[2 * 8192];
  const int L = (blockIdx.x & 7) * 68 + (blockIdx.x >> 3);
  const int n0 = (L >> 5) * 128, m0 = (L & 31) * 128;
  auto epi = [&](int row, int col, const f32x4& v) {
    if (col < NREAL) {
#pragma unroll
      for (int r = 0; r < 4; ++r) C[(size_t)(row + r) * NCOMB + col] = f2bf(v[r]);
    }
  };
  gemm128_body(A, Bw, HID, m0, n0, SA, SB, epi);
}

// grouped qb (768 blocks) + kvb (1024 blocks, epilogue splits KN / VT-transposed)
__global__ __launch_bounds__(256, 2)
void k_gemm_qbkvb(const u16* __restrict__ qa_n, const u16* __restrict__ w_qb,
                  u16* __restrict__ qfull, const u16* __restrict__ kv_n,
                  const u16* __restrict__ w_kvb, u16* __restrict__ KN,
                  u16* __restrict__ VT) {
  __shared__ u16 SA[2 * 8192];
  __shared__ u16 SB[2 * 8192];
  const int bx = blockIdx.x;
  if (bx < 768) {
    const int L = (bx & 7) * 96 + (bx >> 3);
    const int n0 = (L >> 5) * 128, m0 = (L & 31) * 128;
    auto epi = [&](int row, int col, const f32x4& v) {
#pragma unroll
      for (int r = 0; r < 4; ++r) qfull[(size_t)(row + r) * 3072 + col] = f2bf(v[r]);
    };
    gemm128_body(qa_n, w_qb, QL, m0, n0, SA, SB, epi);
  } else {
    const int i = bx - 768;
    const int L = (i & 7) * 128 + (i >> 3);
    const int n0 = (L >> 5) * 128, m0 = (L & 31) * 128;
    auto epi = [&](int row, int col, const f32x4& v) {
      const int h = col >> 8, d = col & 255;
      if (d < 128) {
#pragma unroll
        for (int r = 0; r < 4; ++r) KN[(size_t)(row + r) * 2048 + h * 128 + d] = f2bf(v[r]);
      } else {
        uint2 o; o.x = pack2(v[0], v[1]); o.y = pack2(v[2], v[3]);
        *(uint2*)(VT + ((size_t)((row >> 11) * 16 + h) * 128 + (d - 128)) * SS + (row & (SS - 1))) = o;
      }
    };
    gemm128_body(kv_n, w_kvb, KVL, m0, n0, SA, SB, epi);
  }
}

// o_proj -> fp32 d_out. 512 blocks = exactly 2/CU.
__global__ __launch_bounds__(256, 2)
void k_oproj(const u16* __restrict__ A, const u16* __restrict__ Bw, float* __restrict__ C) {
  __shared__ u16 SA[2 * 8192];
  __shared__ u16 SB[2 * 8192];
  const int L = (blockIdx.x & 7) * 64 + (blockIdx.x >> 3);
  const int n0 = (L >> 5) * 128, m0 = (L & 31) * 128;
  auto epi = [&](int row, int col, const f32x4& v) {
#pragma unroll
    for (int r = 0; r < 4; ++r) C[(size_t)(row + r) * HID + col] = v[r];
  };
  gemm128_body(A, Bw, NH * VD, m0, n0, SA, SB, epi);
}

// ---------------- fused per-token: RMSNorm(q), RMSNorm(kv), rope(k_pe) ----------------
__global__ __launch_bounds__(256)
void k_token(const u16* __restrict__ ac, const float* __restrict__ qw,
             const float* __restrict__ kvw, const int* __restrict__ pos,
             u16* __restrict__ qa_n, u16* __restrict__ kv_n, u16* __restrict__ peR) {
  const int row = blockIdx.x, t = threadIdx.x;
  const u16* xr = ac + (size_t)row * NCOMB;
  float sq = 0.f, skv = 0.f;
  if (t < 192) {
    bf16x8 v = *(const bf16x8*)(xr + t * 8);
#pragma unroll
    for (int j = 0; j < 8; ++j) { float f = bf2f((u16)v[j]); sq += f * f; }
  }
  if (t < 64) {
    bf16x8 v = *(const bf16x8*)(xr + QL + t * 8);
#pragma unroll
    for (int j = 0; j < 8; ++j) { float f = bf2f((u16)v[j]); skv += f * f; }
  }
#pragma unroll
  for (int o = 1; o < 64; o <<= 1) { sq += __shfl_xor(sq, o); skv += __shfl_xor(skv, o); }
  __shared__ float red[4][2];
  if ((t & 63) == 0) { red[t >> 6][0] = sq; red[t >> 6][1] = skv; }
  __syncthreads();
  const float rsq  = rsqrtf((red[0][0] + red[1][0] + red[2][0] + red[3][0]) / (float)QL  + 1e-6f);
  const float rskv = rsqrtf((red[0][1] + red[1][1] + red[2][1] + red[3][1]) / (float)KVL + 1e-6f);
  if (t < 192) {
    bf16x8 v = *(const bf16x8*)(xr + t * 8);
    u32 o4[4];
#pragma unroll
    for (int j = 0; j < 4; ++j)
      o4[j] = pack2(bf2f((u16)v[2 * j]) * rsq * qw[t * 8 + 2 * j],
                    bf2f((u16)v[2 * j + 1]) * rsq * qw[t * 8 + 2 * j + 1]);
    *(uint4*)(qa_n + (size_t)row * QL + t * 8) = *(uint4*)o4;
  }
  if (t < 64) {
    bf16x8 v = *(const bf16x8*)(xr + QL + t * 8);
    u32 o4[4];
#pragma unroll
    for (int j = 0; j < 4; ++j)
      o4[j] = pack2(bf2f((u16)v[2 * j]) * rskv * kvw[t * 8 + 2 * j],
                    bf2f((u16)v[2 * j + 1]) * rskv * kvw[t * 8 + 2 * j + 1]);
    *(uint4*)(kv_n + (size_t)row * KVL + t * 8) = *(uint4*)o4;
  }
  if (t < 32) {
    const u16* src = xr + (QL + KVL) + 2 * t;
    float x0 = bf2f(src[0]), x1 = bf2f(src[1]);
    float ang = (float)pos[row] * __expf(-(float)t * LN1E4_32);
    float sn, cs; sincosf(ang, &sn, &cs);
    *(u32*)(peR + (size_t)row * 64 + 2 * t) = pack2(x0 * cs - x1 * sn, x1 * cs + x0 * sn);
  }
}

// ---------------- causal flash attention (R10 structure + hoisted staging pointers) ----------------
// 1024 blocks x 4 waves, dbuf K and V, one vmcnt(0)+barrier per tile.
// Staging addresses resolved ONCE per thread (KN-vs-peR branch, div/mod, swizzle),
// then advanced by constant strides each tile -> ~45 fewer VALU instr/tile/thread.
__global__ __launch_bounds__(256)
void k_attn(const u16* __restrict__ Qf, const u16* __restrict__ KN,
            const u16* __restrict__ peR, const u16* __restrict__ VT,
            const int* __restrict__ pos, u16* __restrict__ Oa) {
  const int id = blockIdx.x;
  const int xk = id & 7, j = id >> 3;
  const int c = 31 - (j >> 2);
  const int bh = (j & 3) * 8 + xk;
  const int b = bh >> 4, h = bh & 15;
  const int t = threadIdx.x, lane = t & 63, wave = t >> 6;
  const int lq = lane & 15, lg = lane >> 4;
  const int q0 = c * 64 + wave * 16;
  const size_t vb = (size_t)bh * VD * SS;

  __shared__ u16 Ks[2][32 * 192];
  __shared__ u16 Vs[2][128 * 32];
  __shared__ u16 Pl[4][512];
  char* pl = (char*)&Pl[wave][0];
  const int swq = ((lq ^ (lq >> 2)) & 3) << 4;

  // -------- hoisted per-thread staging pointers (advance by const stride/tile) --------
  const u16* srcK0; const u16* srcK1; const u16* srcK2;
  int stK0, stK1, stK2;
  {
    auto mk = [&](int cc, const u16*& p, int& st) {
      int row = cc / 24, sl = cc % 24, sg = sl ^ (row & 7);
      if (sg < 16) { p = KN + (size_t)(b * SS + row) * 2048 + h * 128 + sg * 8; st = 32 * 2048; }
      else         { p = peR + (size_t)(b * SS + row) * 64 + (sg - 16) * 8;     st = 32 * 64; }
    };
    mk(t, srcK0, stK0); mk(t + 256, srcK1, stK1); mk(t + 512, srcK2, stK2);
  }
  const u16* srcV0; const u16* srcV1;
  {
    int r0 = t >> 2, s0l = t & 3;
    srcV0 = VT + vb + (size_t)r0 * SS + (s0l ^ ((r0 >> 1) & 3)) * 8;
    int cc = t + 256, r1 = cc >> 2, s1l = cc & 3;
    srcV1 = VT + vb + (size_t)r1 * SS + (s1l ^ ((r1 >> 1) & 3)) * 8;
  }

  auto stage = [&](int buf) {
    gload_lds16(srcK0, &Ks[buf][0] + t * 8);
    gload_lds16(srcK1, &Ks[buf][0] + (t + 256) * 8);
    gload_lds16(srcK2, &Ks[buf][0] + (t + 512) * 8);
    gload_lds16(srcV0, &Vs[buf][0] + t * 8);
    gload_lds16(srcV1, &Vs[buf][0] + (t + 256) * 8);
    srcK0 += stK0; srcK1 += stK1; srcK2 += stK2;
    srcV0 += 32; srcV1 += 32;
  };

  const int token = b * SS + q0 + lq;
  bf16x8 qf[6];
#pragma unroll
  for (int ch = 0; ch < 6; ++ch)
    qf[ch] = *(const bf16x8*)(Qf + (size_t)token * (NH * QHD) + h * QHD + ch * 32 + lg * 8);
  const float posv = (float)pos[token];
#pragma unroll
  for (int ch = 4; ch < 6; ++ch)
#pragma unroll
    for (int p = 0; p < 4; ++p) {
      const int jj = (ch - 4) * 16 + lg * 4 + p;
      const float ang = posv * __expf(-(float)jj * LN1E4_32);
      float sn, cs; sincosf(ang, &sn, &cs);
      const float x0 = bf2f((u16)qf[ch][2 * p]), x1 = bf2f((u16)qf[ch][2 * p + 1]);
      qf[ch][2 * p]     = (short)f2bf(x0 * cs - x1 * sn);
      qf[ch][2 * p + 1] = (short)f2bf(x1 * cs + x0 * sn);
    }

  float m = -1e30f, lsum = 0.f;     // m in RAW score units
  f32x4 o[8];
#pragma unroll
  for (int vc = 0; vc < 8; ++vc) o[vc] = (f32x4){0.f, 0.f, 0.f, 0.f};

  const int nt = 2 * (c + 1);

  stage(0);
  asm volatile("s_waitcnt vmcnt(0)" ::: "memory");
  __builtin_amdgcn_s_barrier();

  for (int tt = 0; tt < nt; ++tt) {
    const int cur = tt & 1;
    if (tt + 1 < nt) stage(cur ^ 1);
    const int kb = tt * 32;

    if (kb < q0 + 16) {            // wave-uniform skip of fully-masked tiles
      f32x4 slo = (f32x4){0.f, 0.f, 0.f, 0.f};
      f32x4 shi = (f32x4){0.f, 0.f, 0.f, 0.f};
      __builtin_amdgcn_s_setprio(1);
#pragma unroll
      for (int ch = 0; ch < 6; ++ch) {
        const int ps = (ch * 4 + lg) ^ (lq & 7);
        bf16x8 klo = *(const bf16x8*)(&Ks[cur][0] + (lq * 24 + ps) * 8);
        bf16x8 khi = *(const bf16x8*)(&Ks[cur][0] + ((16 + lq) * 24 + ps) * 8);
        slo = __builtin_amdgcn_mfma_f32_16x16x32_bf16(klo, qf[ch], slo, 0, 0, 0);
        shi = __builtin_amdgcn_mfma_f32_16x16x32_bf16(khi, qf[ch], shi, 0, 0, 0);
      }
      __builtin_amdgcn_s_setprio(0);

      float mx;
      if (kb + 32 <= q0) {         // interior tile: no lane masked
        mx = fmaxf(fmaxf(fmaxf(slo[0], slo[1]), fmaxf(slo[2], slo[3])),
                   fmaxf(fmaxf(shi[0], shi[1]), fmaxf(shi[2], shi[3])));
      } else {                     // diagonal tile: mask in raw domain
        const int qrow = q0 + lq;
#pragma unroll
        for (int r = 0; r < 4; ++r) {
          int klo = kb + lg * 4 + r;
          slo[r] = (klo <= qrow)        ? slo[r] : -3e38f;
          shi[r] = ((klo + 16) <= qrow) ? shi[r] : -3e38f;
        }
        mx = fmaxf(fmaxf(fmaxf(slo[0], slo[1]), fmaxf(slo[2], slo[3])),
                   fmaxf(fmaxf(shi[0], shi[1]), fmaxf(shi[2], shi[3])));
      }
      mx = fmaxf(mx, __shfl_xor(mx, 16));
      mx = fmaxf(mx, __shfl_xor(mx, 32));
      if (!__all(mx - m <= THR_RAW)) {
        float mnew = fmaxf(m, mx);
        float fac = fexp2((m - mnew) * SCALE2);
        lsum *= fac;
#pragma unroll
        for (int vc = 0; vc < 8; ++vc) {
          o[vc][0] *= fac; o[vc][1] *= fac; o[vc][2] *= fac; o[vc][3] *= fac;
        }
        m = mnew;
      }
      const float ms = m * SCALE2;
      float p0 = fexp2(fmaf(slo[0], SCALE2, -ms)), p1 = fexp2(fmaf(slo[1], SCALE2, -ms));
      float p2 = fexp2(fmaf(slo[2], SCALE2, -ms)), p3 = fexp2(fmaf(slo[3], SCALE2, -ms));
      float p4 = fexp2(fmaf(shi[0], SCALE2, -ms)), p5 = fexp2(fmaf(shi[1], SCALE2, -ms));
      float p6 = fexp2(fmaf(shi[2], SCALE2, -ms)), p7 = fexp2(fmaf(shi[3], SCALE2, -ms));
      float ps2 = ((p0 + p1) + (p2 + p3)) + ((p4 + p5) + (p6 + p7));
      ps2 += __shfl_xor(ps2, 16);
      ps2 += __shfl_xor(ps2, 32);
      lsum += ps2;

      *(u32*)(pl + lq * 64 + ((8 * lg)          ^ swq)) = cvtpk(p0, p1);
      *(u32*)(pl + lq * 64 + ((8 * lg + 4)      ^ swq)) = cvtpk(p2, p3);
      *(u32*)(pl + lq * 64 + ((32 + 8 * lg)     ^ swq)) = cvtpk(p4, p5);
      *(u32*)(pl + lq * 64 + ((32 + 8 * lg + 4) ^ swq)) = cvtpk(p6, p7);
      bf16x8 pf = *(const bf16x8*)(pl + lq * 64 + ((16 * lg) ^ swq));
      __builtin_amdgcn_s_setprio(1);
#pragma unroll
      for (int vc = 0; vc < 8; ++vc) {
        const int rv = vc * 16 + lq;
        const int psv = lg ^ ((rv >> 1) & 3);
        bf16x8 vf = *(const bf16x8*)(&Vs[cur][0] + rv * 32 + psv * 8);
        o[vc] = __builtin_amdgcn_mfma_f32_16x16x32_bf16(vf, pf, o[vc], 0, 0, 0);
      }
      __builtin_amdgcn_s_setprio(0);
    }

    asm volatile("s_waitcnt vmcnt(0)" ::: "memory");
    __builtin_amdgcn_s_barrier();
  }

  const float inv = 1.0f / lsum;
  u16* orow = Oa + (size_t)token * (NH * VD) + h * VD;
#pragma unroll
  for (int vc = 0; vc < 8; ++vc) {
    *(u32*)(orow + vc * 16 + lg * 4)     = cvtpk(o[vc][0] * inv, o[vc][1] * inv);
    *(u32*)(orow + vc * 16 + lg * 4 + 2) = cvtpk(o[vc][2] * inv, o[vc][3] * inv);
  }
}

// ---------------- host launch ----------------
extern "C" void kernel_launch(void* const* d_in, const int* in_sizes, int n_in,
                              void* d_out, int out_size, void* d_ws, size_t ws_size,
                              hipStream_t stream) {
  (void)in_sizes; (void)n_in; (void)out_size; (void)ws_size;
  const float* hidden  = (const float*)d_in[0];
  const int*   pos     = (const int*)d_in[2];
  const float* q_a_w   = (const float*)d_in[3];
  const float* q_a_ln  = (const float*)d_in[4];
  const float* q_b_w   = (const float*)d_in[5];
  const float* kv_a_w  = (const float*)d_in[6];
  const float* kv_a_ln = (const float*)d_in[7];
  const float* kv_b_w  = (const float*)d_in[8];
  const float* o_w     = (const float*)d_in[9];

  char* ws = (char*)d_ws;
  u16* hid_bf = (u16*)(ws + 0);          // dead after GEMM1; region reused as VT
  u16* VT     = (u16*)(ws + 0);
  u16* w_comb = (u16*)(ws + 16777216);
  u16* w_qb   = (u16*)(ws + 25690112);
  u16* w_kvb  = (u16*)(ws + 35127296);
  u16* w_o    = (u16*)(ws + 39321600);
  u16* ac     = (u16*)(ws + 47710208);   // dead after k_token; reused as attn_o
  u16* attn_o = (u16*)(ws + 47710208);
  u16* qa_n   = (u16*)(ws + 65536000);
  u16* kv_n   = (u16*)(ws + 78118912);
  u16* qfull  = (u16*)(ws + 82313216);
  u16* KN     = (u16*)(ws + 107479040);  // TOK x 2048 compact k_nope
  u16* peR    = (u16*)(ws + 141033472);  // TOK x 64 roped k_pe

  k_f2bf_all<<<23168, 256, 0, stream>>>(hidden, q_a_w, kv_a_w, q_b_w, kv_b_w, o_w,
                                        hid_bf, w_comb, w_comb + QL * HID, w_qb, w_kvb, w_o);
  k_gemm1<<<544, 256, 0, stream>>>(hid_bf, w_comb, ac);
  k_token<<<TOK, 256, 0, stream>>>(ac, q_a_ln, kv_a_ln, pos, qa_n, kv_n, peR);
  k_gemm_qbkvb<<<1792, 256, 0, stream>>>(qa_n, w_qb, qfull, kv_n, w_kvb, KN, VT);
  k_attn<<<1024, 256, 0, stream>>>(qfull, KN, peR, VT, pos, attn_o);
  k_oproj<<<512, 256, 0, stream>>>(attn_o, w_o, (float*)d_out);
}